// Round 6
// baseline (132.543 us; speedup 1.0000x reference)
//
#include <hip/hip_runtime.h>
#include <hip/hip_bf16.h>

// CustomBernsteinLayer: out[b,o] = sum_{i,k} ber[b,i,k] * (coeffs[o,i,k]*weights[o,i])
// ber = (1+t)^k (1-t)^(8-k), t = tanh(x).  With e = exp2(2x*log2e):
//   (1-t) = 2/(e+1) = q, ratio r = e, p0 = q^8, ber_{k+1} = ber_k * r.
// bf16 MFMA GEMM M=16384 N=256 K=2304, per-lane in-register A-gen (validated).
// R13: 16 waves/CU via in-block K-split. R7/R8/R12 (all 8 waves/CU) are
// within 0.5us of each other; R9 (4 waves/CU) +2.1us; both pipes ~75% idle
// (R10 counters), 0 bank conflicts -> latency-bound, occupancy is the only
// untested lever. Block = 128 rows x 64 cols, 8 waves: waves 0-3 do steps
// 0-17 (chunks 0,1), waves 4-7 do steps 18-35 (chunks 2,3), same tile;
// f32 partials merged through LDS in the epilogue. 512 blocks x 512 thr ->
// 2 blocks/CU (64 KB LDS each), 4 waves/SIMD, per-wave chain halves.
// Per-wave inner structure (m=2/n=4 fragments, A-gen, C-layout) unchanged.

#define BDIM 16384
#define IDIM 256
#define ODIM 256
#define NK 9
#define NSTEP 36
#define STEP_ELEMS (ODIM * 64)   // 16384 bf16 (32 KB) per K-step block

typedef short short8 __attribute__((ext_vector_type(8)));
typedef float floatx4 __attribute__((ext_vector_type(4)));

// ---------------------------------------------------------------------------
// prep (validated): wc[step][e] = bf16(coeffs[o,i,k]*weights[o,i]),
// e = (((o>>4)*2 + s)*64 + (o&15) + quad*16)*8 + j, i_local = s*32+quad*8+j,
// step = (i>>6)*9 + k. One coalesced 16B store per thread.
// ---------------------------------------------------------------------------
__global__ __launch_bounds__(256) void prep_wc2(const float* __restrict__ weights,
                                                const float* __restrict__ coeffs,
                                                ushort* __restrict__ wc) {
    int idx  = blockIdx.x * 256 + threadIdx.x;  // 73728 chunks
    int step = idx >> 11;
    int c    = idx & 2047;
    int big    = c >> 6;
    int lane_w = c & 63;
    int o    = (big >> 1) * 16 + (lane_w & 15);
    int s    = big & 1;
    int quad = lane_w >> 4;
    int ic = step / 9;
    int k  = step - ic * 9;
    int i0 = ic * 64 + s * 32 + quad * 8;

    const float* cp = coeffs + (size_t)(o * IDIM + i0) * NK + k;
    float4 w0 = *(const float4*)(weights + o * IDIM + i0);
    float4 w1 = *(const float4*)(weights + o * IDIM + i0 + 4);
    float wv[8] = {w0.x, w0.y, w0.z, w0.w, w1.x, w1.y, w1.z, w1.w};

    union { ushort us[8]; int4 v; __hip_bfloat162 h2[4]; } pk;
#pragma unroll
    for (int j = 0; j < 8; j += 2) {
        float a = cp[(size_t)j * NK] * wv[j];
        float b = cp[(size_t)(j + 1) * NK] * wv[j + 1];
        pk.h2[j >> 1] = __float22bfloat162_rn(make_float2(a, b));
    }
    *(int4*)(wc + (size_t)step * STEP_ELEMS + (size_t)c * 8) = pk.v;
}

// ---------------------------------------------------------------------------
// GEMM: 512 blocks x 512 threads (8 waves), 2 blocks/CU (64 KB LDS each).
//   cg = blk & 3  -> cols cg*64 .. +63 (whole block)
//   rg = blk >> 2 -> rows rg*128 .. +127
//   wave: wl = wave&3 -> rows rb = rg*128 + wl*32; wg = wave>>2 -> K-half
//   (wg=0: steps 0-17 / chunks 0,1; wg=1: steps 18-35 / chunks 2,3).
// Per-lane A state: rows rb + m*16 + (lane&15), m in {0,1};
//   i_local = s*32 + (lane>>4)*8 + j.
// B: cg-slice of each step is a contiguous 8 KB of wc. Groups g=0..8 of
// 2 local steps per half: 4 slices {half,q} (32 KB) staged into
// Blds[g&1][ (half*2+q)*4096 ...] one group ahead via global_load_lds.
// Fragment (n,s) of local step t: Blds[(t>>1)&1][(wg*2+(t&1))*4096
//   + (n*2+s)*512 + lane*8], read as b128.
// Epilogue: wg=1 waves write acc to LDS, wg=0 waves add + store.
// ---------------------------------------------------------------------------
__global__ __launch_bounds__(512, 4) void bern_gemm(const float* __restrict__ x,
                                                    const ushort* __restrict__ wc,
                                                    float* __restrict__ out) {
    __shared__ ushort Blds[2][16384];   // 2 x 32 KB (4 step-slices each)

    const int tid  = threadIdx.x;
    const int wave = tid >> 6;          // 0..7
    const int lane = tid & 63;
    const int wl   = wave & 3;          // row-wave within block
    const int wg   = wave >> 2;         // K-half
    const int cg   = blockIdx.x & 3;
    const int rb   = (blockIdx.x >> 2) * 128 + wl * 32;
    const int lrow = lane & 15;
    const int jseg = (lane >> 4) * 8;      // 0,8,16,24

    float p[2][2][8];   // [m][s][j]: running ber
    float r[2][2][8];   // raw x at load time, then ratio e = exp2(2x log2 e)
    floatx4 acc[2][4];
    floatx4 zero = {0.0f, 0.0f, 0.0f, 0.0f};
#pragma unroll
    for (int m = 0; m < 2; ++m)
#pragma unroll
        for (int n = 0; n < 4; ++n)
            acc[m][n] = zero;

    // load raw x for chunk ic_ into r[][][] (r is dead when this runs:
    // prologue, or top of a kin==8 step — validated in R8/R10)
#define LOAD_XR(ic_)                                                            \
    {                                                                           \
        _Pragma("unroll") for (int m = 0; m < 2; ++m)                           \
        _Pragma("unroll") for (int s = 0; s < 2; ++s) {                         \
            const float* xp = x + (size_t)(rb + m * 16 + lrow) * IDIM           \
                              + (ic_) * 64 + s * 32 + jseg;                     \
            float4 v0 = *(const float4*)(xp);                                   \
            float4 v1 = *(const float4*)(xp + 4);                               \
            r[m][s][0] = v0.x; r[m][s][1] = v0.y;                               \
            r[m][s][2] = v0.z; r[m][s][3] = v0.w;                               \
            r[m][s][4] = v1.x; r[m][s][5] = v1.y;                               \
            r[m][s][6] = v1.z; r[m][s][7] = v1.w;                               \
        }                                                                       \
    }

    // r holds raw x -> p = q^8, r = ratio (p,r dead when this runs)
#define SETUP_FROM_R()                                                          \
    {                                                                           \
        _Pragma("unroll") for (int m = 0; m < 2; ++m)                           \
        _Pragma("unroll") for (int s = 0; s < 2; ++s)                           \
        _Pragma("unroll") for (int e = 0; e < 8; ++e) {                         \
            float t  = __builtin_amdgcn_exp2f(r[m][s][e] * 2.8853900817779268f);\
            float q  = 2.0f * __builtin_amdgcn_rcpf(t + 1.0f);                  \
            float q2 = q * q;                                                   \
            float q4 = q2 * q2;                                                 \
            p[m][s][e] = q4 * q4;                                               \
            r[m][s][e] = t;                                                     \
        }                                                                       \
    }

    // stage group g_ (local steps 2g_,2g_+1 of BOTH halves, 32 KB) into
    // Blds[b_]; 512 threads x 16B cover one 8 KB step-slice per round.
#define STAGE(g_, b_)                                                           \
    {                                                                           \
        _Pragma("unroll") for (int hq = 0; hq < 4; ++hq) {                      \
            int half = hq >> 1, q = hq & 1;                                     \
            int st  = half * 18 + (g_) * 2 + q;                                 \
            int off = wave * 512 + lane * 8;                                    \
            const ushort* sp = wc + (size_t)st * STEP_ELEMS + cg * 4096 + off;  \
            ushort* dp = &Blds[b_][(half * 2 + q) * 4096 + off];                \
            __builtin_amdgcn_global_load_lds(                                   \
                (const __attribute__((address_space(1))) void*)sp,              \
                (__attribute__((address_space(3))) void*)dp, 16, 0, 0);         \
        }                                                                       \
    }

    LOAD_XR(wg * 2);
    SETUP_FROM_R();
    STAGE(0, 0);

#pragma unroll
    for (int g = 0; g < 9; ++g) {
        __syncthreads();            // group g resident (staged 2 steps ago)
        if (g < 8) STAGE(g + 1, (g + 1) & 1);

#pragma unroll
        for (int q = 0; q < 2; ++q) {
            const int t   = g * 2 + q;      // local step 0..17
            const int kin = t % 9;
            // kin==8: r dead -> prefetch next chunk's x at step top so the
            // HBM latency hides under this step's MFMAs
            if (t == 8) LOAD_XR(wg * 2 + 1);

#pragma unroll
            for (int s = 0; s < 2; ++s) {
                // B fragments for this (step, s) from LDS, reused by 2 m's
                short8 bfr[4];
#pragma unroll
                for (int n = 0; n < 4; ++n)
                    bfr[n] = *(const short8*)&Blds[g & 1]
                        [(wg * 2 + q) * 4096 + (n * 2 + s) * 512 + lane * 8];

#pragma unroll
                for (int m = 0; m < 2; ++m) {
                    union { ushort us[8]; short8 v; __hip_bfloat162 h2[4]; } pk;
#pragma unroll
                    for (int e = 0; e < 8; e += 2) {
                        pk.h2[e >> 1] = __float22bfloat162_rn(
                            make_float2(p[m][s][e], p[m][s][e + 1]));
                    }
#pragma unroll
                    for (int n = 0; n < 4; ++n)
                        acc[m][n] = __builtin_amdgcn_mfma_f32_16x16x32_bf16(
                            pk.v, bfr[n], acc[m][n], 0, 0, 0);
                    if (kin < NK - 1)
#pragma unroll
                        for (int e = 0; e < 8; ++e) p[m][s][e] *= r[m][s][e];
                }
            }

            // chunk boundary: build next chunk's basis from prefetched x
            if (t == 8) SETUP_FROM_R();
        }
    }

    // ---- epilogue: merge K-halves via LDS, then store (C/D layout:
    //      col=lane&15, row=(lane>>4)*4+reg) ----
    __syncthreads();                 // all waves done reading Blds
    float* fb = (float*)(&Blds[0][0]) + wl * 2048;   // per-row-wave area, 8 KB
    if (wg == 1) {
#pragma unroll
        for (int m = 0; m < 2; ++m)
#pragma unroll
            for (int n = 0; n < 4; ++n)
#pragma unroll
                for (int reg = 0; reg < 4; ++reg)
                    fb[(((m * 4 + n) * 4) + reg) * 64 + lane] = acc[m][n][reg];
    }
    __syncthreads();
    if (wg == 0) {
#pragma unroll
        for (int m = 0; m < 2; ++m) {
#pragma unroll
            for (int n = 0; n < 4; ++n) {
                int col   = cg * 64 + n * 16 + (lane & 15);
                int rbase = rb + m * 16 + (lane >> 4) * 4;
#pragma unroll
                for (int reg = 0; reg < 4; ++reg) {
                    float v = acc[m][n][reg] +
                              fb[(((m * 4 + n) * 4) + reg) * 64 + lane];
                    out[(size_t)(rbase + reg) * ODIM + col] = v;
                }
            }
        }
    }
#undef LOAD_XR
#undef SETUP_FROM_R
#undef STAGE
}

extern "C" void kernel_launch(void* const* d_in, const int* in_sizes, int n_in,
                              void* d_out, int out_size, void* d_ws, size_t ws_size,
                              hipStream_t stream) {
    const float* x       = (const float*)d_in[0];   // [B, I]
    const float* weights = (const float*)d_in[1];   // [O, I]
    const float* coeffs  = (const float*)d_in[2];   // [O, I, 9]
    float* out = (float*)d_out;                     // [B, O]
    ushort* wc = (ushort*)d_ws;                     // 36 * 32 KB = 1.13 MB

    prep_wc2<<<288, 256, 0, stream>>>(weights, coeffs, wc);
    bern_gemm<<<512, 512, 0, stream>>>(x, wc, out);
}

// Round 7
// 108.210 us; speedup vs baseline: 1.2249x; 1.2249x over previous
//
#include <hip/hip_runtime.h>
#include <hip/hip_bf16.h>

// CustomBernsteinLayer: out[b,o] = sum_{i,k} ber[b,i,k] * (coeffs[o,i,k]*weights[o,i])
// ber = (1+t)^k (1-t)^(8-k), t = tanh(x).  With e = exp2(2x*log2e):
//   (1-t) = 2/(e+1) = q, ratio r = e, p0 = q^8, ber_{k+1} = ber_k * r.
// bf16 MFMA GEMM M=16384 N=256 K=2304, per-lane in-register A-gen (validated).
// R14: TRUE 16 waves/CU. Ledger: all ~34us configs were 8 waves/CU by grid
// (R7/R12: 256 blocks) or LDS (R8); R13's 16-wave try spilled (launch_bounds
// 2nd arg is min BLOCKS/CU: (512,4) -> cap 64 -> 95 MB scratch). Fix: shrink
// wave tile to 32x32 (m=2, n=2): persistent state halves (p32+r32+acc16
// ~ 80 VGPR -> compiles ~100, safely under the 128 cap of (256,4)).
// 1024 blocks x 256 thr (4 waves), block = 128 rows x 32 cols (cg=8,
// R10-validated addressing), LDS 2x16KB dbuf -> 4 blocks/CU, 16 waves/CU
// (4/EU). Per-CU floors unchanged: LDS 11.5us, MFMA 9.3us, VALU ~560cyc/step
// (A-gen dup=8; x re-reads L2-resident). Latency now hidden by TLP.

#define BDIM 16384
#define IDIM 256
#define ODIM 256
#define NK 9
#define NSTEP 36
#define STEP_ELEMS (ODIM * 64)   // 16384 bf16 (32 KB) per K-step block

typedef short short8 __attribute__((ext_vector_type(8)));
typedef float floatx4 __attribute__((ext_vector_type(4)));

// ---------------------------------------------------------------------------
// prep (validated): wc[step][e] = bf16(coeffs[o,i,k]*weights[o,i]),
// e = (((o>>4)*2 + s)*64 + (o&15) + quad*16)*8 + j, i_local = s*32+quad*8+j,
// step = (i>>6)*9 + k. One coalesced 16B store per thread.
// ---------------------------------------------------------------------------
__global__ __launch_bounds__(256) void prep_wc2(const float* __restrict__ weights,
                                                const float* __restrict__ coeffs,
                                                ushort* __restrict__ wc) {
    int idx  = blockIdx.x * 256 + threadIdx.x;  // 73728 chunks
    int step = idx >> 11;
    int c    = idx & 2047;
    int big    = c >> 6;
    int lane_w = c & 63;
    int o    = (big >> 1) * 16 + (lane_w & 15);
    int s    = big & 1;
    int quad = lane_w >> 4;
    int ic = step / 9;
    int k  = step - ic * 9;
    int i0 = ic * 64 + s * 32 + quad * 8;

    const float* cp = coeffs + (size_t)(o * IDIM + i0) * NK + k;
    float4 w0 = *(const float4*)(weights + o * IDIM + i0);
    float4 w1 = *(const float4*)(weights + o * IDIM + i0 + 4);
    float wv[8] = {w0.x, w0.y, w0.z, w0.w, w1.x, w1.y, w1.z, w1.w};

    union { ushort us[8]; int4 v; __hip_bfloat162 h2[4]; } pk;
#pragma unroll
    for (int j = 0; j < 8; j += 2) {
        float a = cp[(size_t)j * NK] * wv[j];
        float b = cp[(size_t)(j + 1) * NK] * wv[j + 1];
        pk.h2[j >> 1] = __float22bfloat162_rn(make_float2(a, b));
    }
    *(int4*)(wc + (size_t)step * STEP_ELEMS + (size_t)c * 8) = pk.v;
}

// ---------------------------------------------------------------------------
// GEMM: 1024 blocks x 256 threads (4 waves), 4 blocks/CU (32 KB LDS each)
// -> 16 waves/CU (4/EU).
//   cg = blk & 7  -> cols cg*32 .. +31 (whole block)
//   rg = blk >> 3 -> wave w: rows rg*128 + w*32 .. +31 (m=2 tiles of 16)
// Per-lane A state: rows rb + m*16 + (lane&15), m in {0,1};
//   i_local = s*32 + (lane>>4)*8 + j.
// B: 32-col slice of each step is a contiguous 4 KB of wc at cg*2048
// (big index cg*4 + n*2 + s, n in {0,1}); groups of 4 steps (16 KB) staged
// into Blds[2][16KB] one group ahead via global_load_lds (1 load/thread/
// step). Fragment (n,s) of step g*4+k4 at Blds[g&1][k4*2048 + (n*2+s)*512
// + lane*8], read as b128 and reused by both m's.
// ---------------------------------------------------------------------------
__global__ __launch_bounds__(256, 4) void bern_gemm(const float* __restrict__ x,
                                                    const ushort* __restrict__ wc,
                                                    float* __restrict__ out) {
    __shared__ ushort Blds[2][8192];   // 2 x 16 KB (4 step-slices each)

    const int tid  = threadIdx.x;
    const int wave = tid >> 6;          // 0..3
    const int lane = tid & 63;
    const int cg   = blockIdx.x & 7;
    const int rb   = (blockIdx.x >> 3) * 128 + wave * 32;
    const int lrow = lane & 15;
    const int jseg = (lane >> 4) * 8;      // 0,8,16,24

    float p[2][2][8];   // [m][s][j]: running ber
    float r[2][2][8];   // raw x at load time, then ratio e = exp2(2x log2 e)
    floatx4 acc[2][2];
    floatx4 zero = {0.0f, 0.0f, 0.0f, 0.0f};
#pragma unroll
    for (int m = 0; m < 2; ++m)
#pragma unroll
        for (int n = 0; n < 2; ++n)
            acc[m][n] = zero;

    // load raw x for chunk ic_ into r[][][] (r is dead when this runs:
    // prologue, or top of a kin==8 step — R8-validated)
#define LOAD_XR(ic_)                                                            \
    {                                                                           \
        _Pragma("unroll") for (int m = 0; m < 2; ++m)                           \
        _Pragma("unroll") for (int s = 0; s < 2; ++s) {                         \
            const float* xp = x + (size_t)(rb + m * 16 + lrow) * IDIM           \
                              + (ic_) * 64 + s * 32 + jseg;                     \
            float4 v0 = *(const float4*)(xp);                                   \
            float4 v1 = *(const float4*)(xp + 4);                               \
            r[m][s][0] = v0.x; r[m][s][1] = v0.y;                               \
            r[m][s][2] = v0.z; r[m][s][3] = v0.w;                               \
            r[m][s][4] = v1.x; r[m][s][5] = v1.y;                               \
            r[m][s][6] = v1.z; r[m][s][7] = v1.w;                               \
        }                                                                       \
    }

    // r holds raw x -> p = q^8, r = ratio (p,r dead when this runs)
#define SETUP_FROM_R()                                                          \
    {                                                                           \
        _Pragma("unroll") for (int m = 0; m < 2; ++m)                           \
        _Pragma("unroll") for (int s = 0; s < 2; ++s)                           \
        _Pragma("unroll") for (int e = 0; e < 8; ++e) {                         \
            float t  = __builtin_amdgcn_exp2f(r[m][s][e] * 2.8853900817779268f);\
            float q  = 2.0f * __builtin_amdgcn_rcpf(t + 1.0f);                  \
            float q2 = q * q;                                                   \
            float q4 = q2 * q2;                                                 \
            p[m][s][e] = q4 * q4;                                               \
            r[m][s][e] = t;                                                     \
        }                                                                       \
    }

    // stage group g_ (4 steps, 16 KB slice) into Blds[b_]; 256 threads x 16B
    // cover one step's 4 KB slice per q-round (1 global_load_lds each).
#define STAGE(g_, b_)                                                           \
    {                                                                           \
        _Pragma("unroll") for (int q = 0; q < 4; ++q) {                         \
            int st  = (g_) * 4 + q;                                             \
            int off = wave * 512 + lane * 8;                                    \
            const ushort* sp = wc + (size_t)st * STEP_ELEMS + cg * 2048 + off;  \
            ushort* dp = &Blds[b_][q * 2048 + off];                             \
            __builtin_amdgcn_global_load_lds(                                   \
                (const __attribute__((address_space(1))) void*)sp,              \
                (__attribute__((address_space(3))) void*)dp, 16, 0, 0);         \
        }                                                                       \
    }

    LOAD_XR(0);
    SETUP_FROM_R();
    STAGE(0, 0);

#pragma unroll
    for (int g = 0; g < 9; ++g) {
        __syncthreads();            // group g resident; prev buf free
        if (g < 8) STAGE(g + 1, (g + 1) & 1);

#pragma unroll
        for (int k4 = 0; k4 < 4; ++k4) {
            const int step = g * 4 + k4;
            const int kin = step % 9;
            // kin==8: r dead -> prefetch next chunk's x at step top so the
            // HBM latency hides under this step's MFMAs (R8-validated)
            if (step == 8 || step == 17 || step == 26) {
                LOAD_XR(step / 9 + 1);
            }

#pragma unroll
            for (int s = 0; s < 2; ++s) {
                // B fragments for this (step, s) from LDS, reused by 2 m's
                short8 bfr[2];
#pragma unroll
                for (int n = 0; n < 2; ++n)
                    bfr[n] = *(const short8*)&Blds[g & 1]
                        [k4 * 2048 + (n * 2 + s) * 512 + lane * 8];

#pragma unroll
                for (int m = 0; m < 2; ++m) {
                    union { ushort us[8]; short8 v; __hip_bfloat162 h2[4]; } pk;
#pragma unroll
                    for (int e = 0; e < 8; e += 2) {
                        pk.h2[e >> 1] = __float22bfloat162_rn(
                            make_float2(p[m][s][e], p[m][s][e + 1]));
                    }
#pragma unroll
                    for (int n = 0; n < 2; ++n)
                        acc[m][n] = __builtin_amdgcn_mfma_f32_16x16x32_bf16(
                            pk.v, bfr[n], acc[m][n], 0, 0, 0);
                    if (kin < NK - 1)
#pragma unroll
                        for (int e = 0; e < 8; ++e) p[m][s][e] *= r[m][s][e];
                }
            }

            // chunk boundary: build next chunk's basis from prefetched x
            if (step == 8 || step == 17 || step == 26) {
                SETUP_FROM_R();
            }
        }
    }

    // ---- epilogue: C/D layout col=lane&15, row=(lane>>4)*4+reg ----
#pragma unroll
    for (int m = 0; m < 2; ++m) {
#pragma unroll
        for (int n = 0; n < 2; ++n) {
            int col   = cg * 32 + n * 16 + (lane & 15);
            int rbase = rb + m * 16 + (lane >> 4) * 4;
#pragma unroll
            for (int reg = 0; reg < 4; ++reg) {
                out[(size_t)(rbase + reg) * ODIM + col] = acc[m][n][reg];
            }
        }
    }
#undef LOAD_XR
#undef SETUP_FROM_R
#undef STAGE
}

extern "C" void kernel_launch(void* const* d_in, const int* in_sizes, int n_in,
                              void* d_out, int out_size, void* d_ws, size_t ws_size,
                              hipStream_t stream) {
    const float* x       = (const float*)d_in[0];   // [B, I]
    const float* weights = (const float*)d_in[1];   // [O, I]
    const float* coeffs  = (const float*)d_in[2];   // [O, I, 9]
    float* out = (float*)d_out;                     // [B, O]
    ushort* wc = (ushort*)d_ws;                     // 36 * 32 KB = 1.13 MB

    prep_wc2<<<288, 256, 0, stream>>>(weights, coeffs, wc);
    bern_gemm<<<1024, 256, 0, stream>>>(x, wc, out);
}

// Round 9
// 95.013 us; speedup vs baseline: 1.3950x; 1.1389x over previous
//
#include <hip/hip_runtime.h>
#include <hip/hip_bf16.h>

// CustomBernsteinLayer: out[b,o] = sum_{i,k} ber[b,i,k] * (coeffs[o,i,k]*weights[o,i])
// ber = (1+t)^k (1-t)^(8-k), t = tanh(x).  With e = exp2(2x*log2e):
//   (1-t) = 2/(e+1) = q, ratio r = e, p0 = q^8, ber_{k+1} = ber_k * r.
// bf16 MFMA GEMM M=16384 N=256 K=2304, per-lane in-register A-gen (validated).
// R16: R15's two fixes with the xq-liveness bug repaired.
// R15 failed (absmax 850): LOAD_XQ(2) at g=2 HEADER clobbered xq before
// step 8's SETUP consumed chunk-1's x (same for g=4 vs step 17).
// Fix: issue LOAD_XQ(next) immediately AFTER SETUP_FROM_XQ at steps 8/17
// (xq dead there; WAR on xq regs + "memory"-clobber WAITVs pin the loads
// inside that g-body). Cover stays ~9 steps. Recounted vmcnt FIFO:
// WAITV[g] = {4,12,4,12,12,12,12,4,0}.
// Kept from R15: (a) XCD-cohort swizzle rg=blk&63, cg=blk>>6 (all 4 cg-
// duplicates of a row-group on ONE XCD -> 1 HBM fetch + 3 L2 hits, no
// chip-wide duplicate-miss burst); (b) full-chunk-deep x prefetch.

#define BDIM 16384
#define IDIM 256
#define ODIM 256
#define NK 9
#define NSTEP 36
#define STEP_ELEMS (ODIM * 64)   // 16384 bf16 (32 KB) per K-step block

typedef short short8 __attribute__((ext_vector_type(8)));
typedef float floatx4 __attribute__((ext_vector_type(4)));

// ---------------------------------------------------------------------------
// prep (validated): wc[step][e] = bf16(coeffs[o,i,k]*weights[o,i]),
// e = (((o>>4)*2 + s)*64 + (o&15) + quad*16)*8 + j, i_local = s*32+quad*8+j,
// step = (i>>6)*9 + k. One coalesced 16B store per thread.
// ---------------------------------------------------------------------------
__global__ __launch_bounds__(256) void prep_wc2(const float* __restrict__ weights,
                                                const float* __restrict__ coeffs,
                                                ushort* __restrict__ wc) {
    int idx  = blockIdx.x * 256 + threadIdx.x;  // 73728 chunks
    int step = idx >> 11;
    int c    = idx & 2047;
    int big    = c >> 6;
    int lane_w = c & 63;
    int o    = (big >> 1) * 16 + (lane_w & 15);
    int s    = big & 1;
    int quad = lane_w >> 4;
    int ic = step / 9;
    int k  = step - ic * 9;
    int i0 = ic * 64 + s * 32 + quad * 8;

    const float* cp = coeffs + (size_t)(o * IDIM + i0) * NK + k;
    float4 w0 = *(const float4*)(weights + o * IDIM + i0);
    float4 w1 = *(const float4*)(weights + o * IDIM + i0 + 4);
    float wv[8] = {w0.x, w0.y, w0.z, w0.w, w1.x, w1.y, w1.z, w1.w};

    union { ushort us[8]; int4 v; __hip_bfloat162 h2[4]; } pk;
#pragma unroll
    for (int j = 0; j < 8; j += 2) {
        float a = cp[(size_t)j * NK] * wv[j];
        float b = cp[(size_t)(j + 1) * NK] * wv[j + 1];
        pk.h2[j >> 1] = __float22bfloat162_rn(make_float2(a, b));
    }
    *(int4*)(wc + (size_t)step * STEP_ELEMS + (size_t)c * 8) = pk.v;
}

// ---------------------------------------------------------------------------
// GEMM: 256 blocks x 512 threads (8 waves), 1 block/CU (96 KB LDS).
//   rg = blk & 63 -> rows rg*256 .. +255  (XCD = blk%8 = rg%8: all cg-
//   duplicates of a row-group share one XCD/L2)
//   cg = blk >> 6 -> cols cg*64 .. +63 (whole block)
//   wave w: rows rg*256 + w*32 .. +31 (m=2 tiles of 16)
// Per-lane A state: rows rb + m*16 + (lane&15), m in {0,1};
//   i_local = s*32 + (lane>>4)*8 + j.
// B: cg-slice of each step is a contiguous 8 KB of wc; groups of 4 steps
// (32 KB) staged into Blds[3] TWO groups ahead via global_load_lds; fragment
// (n,s) of step g*4+k4 at Blds[g%3][k4*4096 + (n*2+s)*512 + lane*8] (b128).
// Raw s_barrier + counted vmcnt per group header; never drains mid-loop.
// ---------------------------------------------------------------------------
__global__ __launch_bounds__(512, 2) void bern_gemm(const float* __restrict__ x,
                                                    const ushort* __restrict__ wc,
                                                    float* __restrict__ out) {
    __shared__ ushort Blds[3][16384];   // 3 x 32 KB

    const int tid  = threadIdx.x;
    const int wave = tid >> 6;          // 0..7
    const int lane = tid & 63;
    const int cg   = blockIdx.x >> 6;   // 0..3 (swizzled: co-XCD duplicates)
    const int rb   = (blockIdx.x & 63) * 256 + wave * 32;
    const int lrow = lane & 15;
    const int jseg = (lane >> 4) * 8;      // 0,8,16,24

    float p[2][2][8];    // [m][s][j]: running ber
    float r[2][2][8];    // ratio e = exp2(2x log2 e), live all chunk
    float xq[2][2][8];   // raw-x prefetch buffer (filled a full chunk early)
    floatx4 acc[2][4];
    floatx4 zero = {0.0f, 0.0f, 0.0f, 0.0f};
#pragma unroll
    for (int m = 0; m < 2; ++m)
#pragma unroll
        for (int n = 0; n < 4; ++n)
            acc[m][n] = zero;

    // load raw x for chunk ic_ into xq (xq is dead when this runs)
#define LOAD_XQ(ic_)                                                            \
    {                                                                           \
        _Pragma("unroll") for (int m = 0; m < 2; ++m)                           \
        _Pragma("unroll") for (int s = 0; s < 2; ++s) {                         \
            const float* xp = x + (size_t)(rb + m * 16 + lrow) * IDIM           \
                              + (ic_) * 64 + s * 32 + jseg;                     \
            float4 v0 = *(const float4*)(xp);                                   \
            float4 v1 = *(const float4*)(xp + 4);                               \
            xq[m][s][0] = v0.x; xq[m][s][1] = v0.y;                             \
            xq[m][s][2] = v0.z; xq[m][s][3] = v0.w;                             \
            xq[m][s][4] = v1.x; xq[m][s][5] = v1.y;                             \
            xq[m][s][6] = v1.z; xq[m][s][7] = v1.w;                             \
        }                                                                       \
    }

    // xq holds raw x -> p = q^8, r = ratio (p,r dead when this runs)
#define SETUP_FROM_XQ()                                                         \
    {                                                                           \
        _Pragma("unroll") for (int m = 0; m < 2; ++m)                           \
        _Pragma("unroll") for (int s = 0; s < 2; ++s)                           \
        _Pragma("unroll") for (int e = 0; e < 8; ++e) {                         \
            float t  = __builtin_amdgcn_exp2f(xq[m][s][e] * 2.8853900817779268f);\
            float q  = 2.0f * __builtin_amdgcn_rcpf(t + 1.0f);                  \
            float q2 = q * q;                                                   \
            float q4 = q2 * q2;                                                 \
            p[m][s][e] = q4 * q4;                                               \
            r[m][s][e] = t;                                                     \
        }                                                                       \
    }

    // stage group g_ (4 steps, 32 KB cg-slice) into Blds[b_]; 512 threads x
    // 16B cover one step's 8 KB slice per q-round (4 loads/thread total).
#define STAGE(g_, b_)                                                           \
    {                                                                           \
        _Pragma("unroll") for (int q = 0; q < 4; ++q) {                         \
            int st  = (g_) * 4 + q;                                             \
            int off = wave * 512 + lane * 8;                                    \
            const ushort* sp = wc + (size_t)st * STEP_ELEMS + cg * 4096 + off;  \
            ushort* dp = &Blds[b_][q * 4096 + off];                             \
            __builtin_amdgcn_global_load_lds(                                   \
                (const __attribute__((address_space(1))) void*)sp,              \
                (__attribute__((address_space(3))) void*)dp, 16, 0, 0);         \
        }                                                                       \
    }

#define WAITV(n_) asm volatile("s_waitcnt vmcnt(" #n_ ")" ::: "memory")

    LOAD_XQ(0);
    SETUP_FROM_XQ();   // compiler waits xq0 here; then loads below
    STAGE(0, 0);       // 4 loads in flight
    STAGE(1, 1);       // 8 loads in flight

#pragma unroll
    for (int g = 0; g < 9; ++g) {
        // wait for stage(g) (oldest). Loads issued after stage(g)'s last:
        // g0: stage1=4            | g1: xq1(8)+stage2=12 | g2: stage3=4
        // g3: stage4+xq2=12       | g4: xq2(8)+stage5=12 | g5: stage6+xq3=12
        // g6: xq3(8)+stage7=12    | g7: stage8=4         | g8: 0
        if (g == 0 || g == 2 || g == 7) { WAITV(4); }
        else if (g == 8)                { WAITV(0); }
        else                            { WAITV(12); }
        __builtin_amdgcn_s_barrier();
        __builtin_amdgcn_sched_barrier(0);

        // chunk-1 x prefetch at g=0 header (xq dead since prologue SETUP);
        // chunks 2,3 are prefetched inside the k4 loop right after their
        // predecessor's SETUP consumes xq (steps 8, 17).
        if (g == 0) LOAD_XQ(1);
        if (g < 7) STAGE(g + 2, (g + 2) % 3);

        const int bg = g % 3;
#pragma unroll
        for (int k4 = 0; k4 < 4; ++k4) {
            const int step = g * 4 + k4;
            const int kin = step % 9;

#pragma unroll
            for (int s = 0; s < 2; ++s) {
                // B fragments for this (step, s) from LDS, reused by 2 m's
                short8 bfr[4];
#pragma unroll
                for (int n = 0; n < 4; ++n)
                    bfr[n] = *(const short8*)&Blds[bg]
                        [k4 * 4096 + (n * 2 + s) * 512 + lane * 8];

#pragma unroll
                for (int m = 0; m < 2; ++m) {
                    union { ushort us[8]; short8 v; __hip_bfloat162 h2[4]; } pk;
#pragma unroll
                    for (int e = 0; e < 8; e += 2) {
                        pk.h2[e >> 1] = __float22bfloat162_rn(
                            make_float2(p[m][s][e], p[m][s][e + 1]));
                    }
#pragma unroll
                    for (int n = 0; n < 4; ++n)
                        acc[m][n] = __builtin_amdgcn_mfma_f32_16x16x32_bf16(
                            pk.v, bfr[n], acc[m][n], 0, 0, 0);
                    if (kin < NK - 1)
#pragma unroll
                        for (int e = 0; e < 8; ++e) p[m][s][e] *= r[m][s][e];
                }
            }

            // chunk boundary (kin==8): old p,r dead; build next chunk's
            // basis from prefetched xq, THEN immediately re-arm xq with the
            // following chunk's x (xq dead right after SETUP; ~9 steps of
            // latency cover until its consumption).
            if (step == 8 || step == 17 || step == 26) {
                SETUP_FROM_XQ();
                if (step == 8)  LOAD_XQ(2);
                if (step == 17) LOAD_XQ(3);
            }
        }
    }

    // ---- epilogue: C/D layout col=lane&15, row=(lane>>4)*4+reg ----
#pragma unroll
    for (int m = 0; m < 2; ++m) {
#pragma unroll
        for (int n = 0; n < 4; ++n) {
            int col   = cg * 64 + n * 16 + (lane & 15);
            int rbase = rb + m * 16 + (lane >> 4) * 4;
#pragma unroll
            for (int reg = 0; reg < 4; ++reg) {
                out[(size_t)(rbase + reg) * ODIM + col] = acc[m][n][reg];
            }
        }
    }
#undef LOAD_XQ
#undef SETUP_FROM_XQ
#undef STAGE
#undef WAITV
}

extern "C" void kernel_launch(void* const* d_in, const int* in_sizes, int n_in,
                              void* d_out, int out_size, void* d_ws, size_t ws_size,
                              hipStream_t stream) {
    const float* x       = (const float*)d_in[0];   // [B, I]
    const float* weights = (const float*)d_in[1];   // [O, I]
    const float* coeffs  = (const float*)d_in[2];   // [O, I, 9]
    float* out = (float*)d_out;                     // [B, O]
    ushort* wc = (ushort*)d_ws;                     // 36 * 32 KB = 1.13 MB

    prep_wc2<<<288, 256, 0, stream>>>(weights, coeffs, wc);
    bern_gemm<<<256, 512, 0, stream>>>(x, wc, out);
}